// Round 9
// baseline (49.918 us; speedup 1.0000x reference)
//
#include <hip/hip_runtime.h>

// GaussianAttention: y[b,s,i,j] = exp(-dist(b,i,j)^2 / (2*sigma_s^2))
// dist = L1 distance over D=3 dims; sigma_s = multiplier * base^s.
// Shape constants for this problem instance (fixed by the harness):
constexpr int B = 2;
constexpr int N = 2048;
constexpr int D = 3;
constexpr int H = 8;

// R8: one block per (b,i) row; each thread handles 8 consecutive j
//     (two float4 quads). Halves block/wave count vs R5 -> amortizes c2
//     setup + row loads + launch ramp. IEEE divides -> v_rcp builtins.
// R7 lesson kept: plain float4 stores (nontemporal bypassed L2 write
//     aggregation and cost +48%).
__global__ __launch_bounds__(256) void gauss_attn_kernel(
    const float* __restrict__ x,       // [B,N,D]
    const float* __restrict__ mult,    // [1]
    const float* __restrict__ base,    // [1]
    float* __restrict__ out)           // [B,H,N,N]
{
    const int row = blockIdx.x;          // b*N + i
    const int b   = row >> 11;           // row / N
    const int i   = row & (N - 1);
    const int j0  = threadIdx.x * 8;     // 256 threads * 8 j = 2048 = N

    // Per-head exponent scale: c2[s] = log2(e) / (2 * sigma_s^2).
    // v_rcp approx (~1 ulp) instead of IEEE divide sequences.
    const float m  = mult[0];
    const float bs = base[0];
    const float LOG2E = 1.4426950408889634f;
    const float c0     = 0.5f * LOG2E * __builtin_amdgcn_rcpf(m * m);
    const float inv_b2 = __builtin_amdgcn_rcpf(bs * bs);
    float c2[H];
    c2[0] = c0;
    #pragma unroll
    for (int s = 1; s < H; ++s) c2[s] = c2[s - 1] * inv_b2;

    // Row-anchor point (uniform across block -> scalar loads).
    const float xi0 = x[row * 3 + 0];
    const float xi1 = x[row * 3 + 1];
    const float xi2 = x[row * 3 + 2];

    // 8 j-points = 24 consecutive floats = 6 aligned float4 loads.
    const float4* xj4 = reinterpret_cast<const float4*>(x + (size_t)(b * N + j0) * 3);
    float jx[8], jy[8], jz[8];
    #pragma unroll
    for (int g = 0; g < 2; ++g) {
        const float4 a0 = xj4[g * 3 + 0];
        const float4 a1 = xj4[g * 3 + 1];
        const float4 a2 = xj4[g * 3 + 2];
        jx[g * 4 + 0] = a0.x; jy[g * 4 + 0] = a0.y; jz[g * 4 + 0] = a0.z;
        jx[g * 4 + 1] = a0.w; jy[g * 4 + 1] = a1.x; jz[g * 4 + 1] = a1.y;
        jx[g * 4 + 2] = a1.z; jy[g * 4 + 2] = a1.w; jz[g * 4 + 2] = a2.x;
        jx[g * 4 + 3] = a2.y; jy[g * 4 + 3] = a2.z; jz[g * 4 + 3] = a2.w;
    }

    float t[8];
    #pragma unroll
    for (int q = 0; q < 8; ++q) {
        const float d = fabsf(xi0 - jx[q]) + fabsf(xi1 - jy[q]) + fabsf(xi2 - jz[q]);
        t[q] = -(d * d);
    }

    // 8 heads x 2 quads: one mul + one v_exp_f32 per element, float4 stores.
    #pragma unroll
    for (int s = 0; s < H; ++s) {
        float* dst = out + ((size_t)(b * H + s) * N + i) * N + j0;
        #pragma unroll
        for (int g = 0; g < 2; ++g) {
            float4 v;
            v.x = __builtin_amdgcn_exp2f(t[g * 4 + 0] * c2[s]);
            v.y = __builtin_amdgcn_exp2f(t[g * 4 + 1] * c2[s]);
            v.z = __builtin_amdgcn_exp2f(t[g * 4 + 2] * c2[s]);
            v.w = __builtin_amdgcn_exp2f(t[g * 4 + 3] * c2[s]);
            reinterpret_cast<float4*>(dst)[g] = v;
        }
    }
}

extern "C" void kernel_launch(void* const* d_in, const int* in_sizes, int n_in,
                              void* d_out, int out_size, void* d_ws, size_t ws_size,
                              hipStream_t stream) {
    const float* x    = (const float*)d_in[0];
    const float* mult = (const float*)d_in[1];
    const float* base = (const float*)d_in[2];
    float* out = (float*)d_out;

    const int threads = 256;
    dim3 grid(B * N);                      // 4096 blocks, one per (b,i) row
    gauss_attn_kernel<<<grid, threads, 0, stream>>>(x, mult, base, out);
}

// Round 11
// 45.444 us; speedup vs baseline: 1.0984x; 1.0984x over previous
//
#include <hip/hip_runtime.h>

// GaussianAttention: y[b,s,i,j] = exp(-dist(b,i,j)^2 / (2*sigma_s^2))
// dist = L1 distance over D=3 dims; sigma_s = multiplier * base^s.
// Shape constants for this problem instance (fixed by the harness):
constexpr int B = 2;
constexpr int N = 2048;
constexpr int D = 3;
constexpr int H = 8;

// R9: revert to R7 layout — 4 j/thread so each wave store instruction writes
//     64 lanes x 16B = 1KB CONTIGUOUS (R8's 8 j/thread interleaved two
//     instructions per 64B line and cost +10%). Keep rcpf + amdgcn_exp2f.
// R7 lesson: plain float4 stores (nontemporal bypassed L2 write aggregation,
//     +48%).
__global__ __launch_bounds__(256) void gauss_attn_kernel(
    const float* __restrict__ x,       // [B,N,D]
    const float* __restrict__ mult,    // [1]
    const float* __restrict__ base,    // [1]
    float* __restrict__ out)           // [B,H,N,N]
{
    const int row = blockIdx.y;          // b*N + i
    const int b   = row >> 11;           // row / N
    const int i   = row & (N - 1);
    const int j0  = (blockIdx.x * blockDim.x + threadIdx.x) * 4;

    // Per-head exponent scale: c2[s] = log2(e) / (2 * sigma_s^2).
    // v_rcp approx (~1 ulp) instead of IEEE divide sequences.
    const float m  = mult[0];
    const float bs = base[0];
    const float LOG2E = 1.4426950408889634f;
    const float c0     = 0.5f * LOG2E * __builtin_amdgcn_rcpf(m * m);
    const float inv_b2 = __builtin_amdgcn_rcpf(bs * bs);
    float c2[H];
    c2[0] = c0;
    #pragma unroll
    for (int s = 1; s < H; ++s) c2[s] = c2[s - 1] * inv_b2;

    // Row-anchor point (uniform across block -> scalar loads).
    const float xi0 = x[row * 3 + 0];
    const float xi1 = x[row * 3 + 1];
    const float xi2 = x[row * 3 + 2];

    // 4 j-points = 12 consecutive floats = 3 aligned float4 loads.
    const float4* xj4 = reinterpret_cast<const float4*>(x + (size_t)(b * N + j0) * 3);
    const float4 a0 = xj4[0];
    const float4 a1 = xj4[1];
    const float4 a2 = xj4[2];

    const float jx[4] = {a0.x, a0.w, a1.z, a2.y};
    const float jy[4] = {a0.y, a1.x, a1.w, a2.z};
    const float jz[4] = {a0.z, a1.y, a2.x, a2.w};

    float t[4];
    #pragma unroll
    for (int q = 0; q < 4; ++q) {
        const float d = fabsf(xi0 - jx[q]) + fabsf(xi1 - jy[q]) + fabsf(xi2 - jz[q]);
        t[q] = -(d * d);
    }

    // 8 heads: one mul + one v_exp_f32 per element, float4 coalesced stores.
    #pragma unroll
    for (int s = 0; s < H; ++s) {
        float4 v;
        v.x = __builtin_amdgcn_exp2f(t[0] * c2[s]);
        v.y = __builtin_amdgcn_exp2f(t[1] * c2[s]);
        v.z = __builtin_amdgcn_exp2f(t[2] * c2[s]);
        v.w = __builtin_amdgcn_exp2f(t[3] * c2[s]);
        float* dst = out + ((size_t)(b * H + s) * N + i) * N + j0;
        *reinterpret_cast<float4*>(dst) = v;
    }
}

extern "C" void kernel_launch(void* const* d_in, const int* in_sizes, int n_in,
                              void* d_out, int out_size, void* d_ws, size_t ws_size,
                              hipStream_t stream) {
    const float* x    = (const float*)d_in[0];
    const float* mult = (const float*)d_in[1];
    const float* base = (const float*)d_in[2];
    float* out = (float*)d_out;

    const int threads = 256;
    dim3 grid(N / (threads * 4), B * N);   // (2, 4096)
    gauss_attn_kernel<<<grid, threads, 0, stream>>>(x, mult, base, out);
}

// Round 12
// 45.269 us; speedup vs baseline: 1.1027x; 1.0039x over previous
//
#include <hip/hip_runtime.h>

// GaussianAttention: y[b,s,i,j] = exp(-dist(b,i,j)^2 / (2*sigma_s^2))
// dist = L1 distance over D=3 dims; sigma_s = multiplier * base^s.
// Shape constants for this problem instance (fixed by the harness):
constexpr int B = 2;
constexpr int N = 2048;
constexpr int D = 3;
constexpr int H = 8;

// R11: rotate per-block head-plane order (s = (k+row)&7) to decorrelate the
//      16MiB-strided plane walk across concurrent blocks (HBM channel-phase
//      aliasing probe). c2(s) computed closed-form (c0 * 2^(-2 s log2 bs))
//      to avoid runtime-indexed array -> scratch.
// R9 lesson: 4 j/thread -> each wave store = 1KB contiguous (8 j/t cost +10%).
// R7 lesson: plain float4 stores (nontemporal cost +48%).
__global__ __launch_bounds__(256) void gauss_attn_kernel(
    const float* __restrict__ x,       // [B,N,D]
    const float* __restrict__ mult,    // [1]
    const float* __restrict__ base,    // [1]
    float* __restrict__ out)           // [B,H,N,N]
{
    const int row = blockIdx.y;          // b*N + i
    const int b   = row >> 11;           // row / N
    const int i   = row & (N - 1);
    const int j0  = (blockIdx.x * blockDim.x + threadIdx.x) * 4;

    // c2(s) = log2(e) / (2 * sigma_s^2) = c0 * bs^(-2s)
    const float m  = mult[0];
    const float bs = base[0];
    const float LOG2E = 1.4426950408889634f;
    const float c0  = 0.5f * LOG2E * __builtin_amdgcn_rcpf(m * m);
    const float l2b = __builtin_amdgcn_logf(bs);   // log2(bs)

    // Row-anchor point (uniform across block -> scalar loads).
    const float xi0 = x[row * 3 + 0];
    const float xi1 = x[row * 3 + 1];
    const float xi2 = x[row * 3 + 2];

    // 4 j-points = 12 consecutive floats = 3 aligned float4 loads.
    const float4* xj4 = reinterpret_cast<const float4*>(x + (size_t)(b * N + j0) * 3);
    const float4 a0 = xj4[0];
    const float4 a1 = xj4[1];
    const float4 a2 = xj4[2];

    const float jx[4] = {a0.x, a0.w, a1.z, a2.y};
    const float jy[4] = {a0.y, a1.x, a1.w, a2.z};
    const float jz[4] = {a0.z, a1.y, a2.x, a2.w};

    float t[4];
    #pragma unroll
    for (int q = 0; q < 4; ++q) {
        const float d = fabsf(xi0 - jx[q]) + fabsf(xi1 - jy[q]) + fabsf(xi2 - jz[q]);
        t[q] = -(d * d);
    }

    // 8 heads, visited in row-rotated order so concurrent blocks spread
    // across all 8 16MiB-strided planes at any instant.
    const int srot = row & 7;
    #pragma unroll
    for (int k = 0; k < H; ++k) {
        const int s = (k + srot) & 7;
        const float c2s = c0 * __builtin_amdgcn_exp2f(-2.0f * l2b * (float)s);
        float4 v;
        v.x = __builtin_amdgcn_exp2f(t[0] * c2s);
        v.y = __builtin_amdgcn_exp2f(t[1] * c2s);
        v.z = __builtin_amdgcn_exp2f(t[2] * c2s);
        v.w = __builtin_amdgcn_exp2f(t[3] * c2s);
        float* dst = out + ((size_t)(b * H + s) * N + i) * N + j0;
        *reinterpret_cast<float4*>(dst) = v;
    }
}

extern "C" void kernel_launch(void* const* d_in, const int* in_sizes, int n_in,
                              void* d_out, int out_size, void* d_ws, size_t ws_size,
                              hipStream_t stream) {
    const float* x    = (const float*)d_in[0];
    const float* mult = (const float*)d_in[1];
    const float* base = (const float*)d_in[2];
    float* out = (float*)d_out;

    const int threads = 256;
    dim3 grid(N / (threads * 4), B * N);   // (2, 4096)
    gauss_attn_kernel<<<grid, threads, 0, stream>>>(x, mult, base, out);
}

// Round 13
// 44.770 us; speedup vs baseline: 1.1150x; 1.0111x over previous
//
#include <hip/hip_runtime.h>

// GaussianAttention: y[b,s,i,j] = exp(-dist(b,i,j)^2 / (2*sigma_s^2))
// dist = L1 distance over D=3 dims; sigma_s = multiplier * base^s.
// Shape constants for this problem instance (fixed by the harness):
constexpr int B = 2;
constexpr int N = 2048;
constexpr int D = 3;
constexpr int H = 8;

// R12: halve block count (4096 blocks) by giving each thread TWO quads
//      spaced 1024 floats apart — unlike R8, every wave store instruction
//      still covers 64 lanes x 16B = 1KB CONTIGUOUS. Probes whether
//      per-block setup/dispatch ramp is part of the residual gap to the
//      ~7.1 TB/s fill-rate ceiling.
// R11: plane-order rotation = neutral (channel-phase aliasing refuted).
// R9 lesson: per-instruction wave contiguity is mandatory (+10% if broken).
// R7 lesson: plain float4 stores (nontemporal cost +48%).
__global__ __launch_bounds__(256) void gauss_attn_kernel(
    const float* __restrict__ x,       // [B,N,D]
    const float* __restrict__ mult,    // [1]
    const float* __restrict__ base,    // [1]
    float* __restrict__ out)           // [B,H,N,N]
{
    const int row = blockIdx.x;          // b*N + i
    const int b   = row >> 11;           // row / N
    const int i   = row & (N - 1);
    const int jA  = threadIdx.x * 4;     // quad 0: j in [0, 1024)
    // quad 1: jA + 1024                 // j in [1024, 2048)

    // Per-head exponent scale: c2[s] = log2(e) / (2 * sigma_s^2).
    const float m  = mult[0];
    const float bs = base[0];
    const float LOG2E = 1.4426950408889634f;
    const float c0     = 0.5f * LOG2E * __builtin_amdgcn_rcpf(m * m);
    const float inv_b2 = __builtin_amdgcn_rcpf(bs * bs);
    float c2[H];
    c2[0] = c0;
    #pragma unroll
    for (int s = 1; s < H; ++s) c2[s] = c2[s - 1] * inv_b2;

    // Row-anchor point (uniform across block -> scalar loads).
    const float xi0 = x[row * 3 + 0];
    const float xi1 = x[row * 3 + 1];
    const float xi2 = x[row * 3 + 2];

    // Two 4-j quads, 1024 apart: each = 3 aligned float4 loads.
    float t[2][4];
    #pragma unroll
    for (int g = 0; g < 2; ++g) {
        const int jq = jA + g * 1024;
        const float4* xj4 = reinterpret_cast<const float4*>(x + (size_t)(b * N + jq) * 3);
        const float4 a0 = xj4[0];
        const float4 a1 = xj4[1];
        const float4 a2 = xj4[2];
        const float jx[4] = {a0.x, a0.w, a1.z, a2.y};
        const float jy[4] = {a0.y, a1.x, a1.w, a2.z};
        const float jz[4] = {a0.z, a1.y, a2.x, a2.w};
        #pragma unroll
        for (int q = 0; q < 4; ++q) {
            const float d = fabsf(xi0 - jx[q]) + fabsf(xi1 - jy[q]) + fabsf(xi2 - jz[q]);
            t[g][q] = -(d * d);
        }
    }

    // 8 heads x 2 quads: one mul + one v_exp_f32 per element; each store
    // instruction is wave-contiguous (1KB).
    #pragma unroll
    for (int s = 0; s < H; ++s) {
        float* dst = out + ((size_t)(b * H + s) * N + i) * N + jA;
        #pragma unroll
        for (int g = 0; g < 2; ++g) {
            float4 v;
            v.x = __builtin_amdgcn_exp2f(t[g][0] * c2[s]);
            v.y = __builtin_amdgcn_exp2f(t[g][1] * c2[s]);
            v.z = __builtin_amdgcn_exp2f(t[g][2] * c2[s]);
            v.w = __builtin_amdgcn_exp2f(t[g][3] * c2[s]);
            *reinterpret_cast<float4*>(dst + g * 1024) = v;
        }
    }
}

extern "C" void kernel_launch(void* const* d_in, const int* in_sizes, int n_in,
                              void* d_out, int out_size, void* d_ws, size_t ws_size,
                              hipStream_t stream) {
    const float* x    = (const float*)d_in[0];
    const float* mult = (const float*)d_in[1];
    const float* base = (const float*)d_in[2];
    float* out = (float*)d_out;

    const int threads = 256;
    dim3 grid(B * N);                      // 4096 blocks, one per (b,i) row
    gauss_attn_kernel<<<grid, threads, 0, stream>>>(x, mult, base, out);
}